// Round 4
// baseline (238.010 us; speedup 1.0000x reference)
//
#include <hip/hip_runtime.h>
#include <hip/hip_bf16.h>
#include <math.h>

// Problem constants (fixed by the reference).
constexpr int Ac = 16;    // actions
constexpr int Bc = 32;    // batch
constexpr int Lc = 1024;  // sequence
constexpr int Xc = 1024;  // x feature
constexpr int Yc = 1024;  // y feature
constexpr int Cc = Ac + Bc;   // 48 combined coefficient rows
constexpr int NCH = 64;       // y-chunks in k1 (Yc/16)

// ---------------------------------------------------------------------------
// Wave/block reduction helpers (wave = 64 lanes on CDNA)
// ---------------------------------------------------------------------------
__device__ __forceinline__ float waveReduceSum(float v) {
#pragma unroll
    for (int off = 32; off > 0; off >>= 1) v += __shfl_down(v, off, 64);
    return v;
}

__device__ __forceinline__ float waveReduceMax(float v) {
#pragma unroll
    for (int off = 32; off > 0; off >>= 1) v = fmaxf(v, __shfl_down(v, off, 64));
    return v;
}

// ---------------------------------------------------------------------------
// k1: partial[yc][j][x] = sum_{y in chunk yc} C[j,y] * W[y,x]
// C rows 0..15 = wa_h, rows 16..47 = y. Pure coalesced stores — no atomics,
// no zero-init needed (every element overwritten; k2 reduces over yc).
// grid (X/256=4, Yc/16=64) = 256 blocks (1/CU).
// ---------------------------------------------------------------------------
__global__ __launch_bounds__(256) void k1_proj(
        const float* __restrict__ weight, const float* __restrict__ yv,
        const float* __restrict__ wa_h, float* __restrict__ partial) {
    const int x  = blockIdx.x * 256 + threadIdx.x;
    const int y0 = blockIdx.y * 16;

    __shared__ float cLDS[Cc][16];  // 3 KiB

#pragma unroll
    for (int k = 0; k < 3; ++k) {
        const int idx = threadIdx.x + k * 256;
        const int row = idx >> 4;
        const int col = idx & 15;
        cLDS[row][col] = (row < Ac) ? wa_h[row * Yc + y0 + col]
                                    : yv[(row - Ac) * Yc + y0 + col];
    }

    float w[16];
#pragma unroll
    for (int t = 0; t < 16; ++t) w[t] = weight[(size_t)(y0 + t) * Xc + x];

    __syncthreads();

    float acc[Cc];
#pragma unroll
    for (int j = 0; j < Cc; ++j) acc[j] = 0.0f;

    const float4* cvec = (const float4*)cLDS;
#pragma unroll
    for (int j = 0; j < Cc; ++j) {
#pragma unroll
        for (int q = 0; q < 4; ++q) {
            const float4 c = cvec[j * 4 + q];  // LDS b128 broadcast
            acc[j] = fmaf(w[q * 4 + 0], c.x, acc[j]);
            acc[j] = fmaf(w[q * 4 + 1], c.y, acc[j]);
            acc[j] = fmaf(w[q * 4 + 2], c.z, acc[j]);
            acc[j] = fmaf(w[q * 4 + 3], c.w, acc[j]);
        }
    }

    float* dst = partial + ((size_t)blockIdx.y * Cc) * Xc + x;
#pragma unroll
    for (int j = 0; j < Cc; ++j) dst[j * Xc] = acc[j];
}

// ---------------------------------------------------------------------------
// k2: per action a (block), reduce partials -> s_raw row, softmax_x, then for
// each b with actions[b]==a: reduce yW row from partials, Wy = yW*p + bias.
// grid: 16 blocks x 1024 threads (thread = one x column).
// All partial traffic is L2-resident (12 MB just written by k1).
// ---------------------------------------------------------------------------
__global__ __launch_bounds__(1024) void k2_softmax_wy(
        const float* __restrict__ partial, const float* __restrict__ bias,
        const int* __restrict__ actions, float* __restrict__ Wy) {
    const int a    = blockIdx.x;
    const int x    = threadIdx.x;
    const int wave = threadIdx.x >> 6;
    const int lane = threadIdx.x & 63;
    __shared__ float smax[16];
    __shared__ float ssum[16];

    // Reduce this action's score column over the 64 y-chunks.
    float s = 0.0f;
#pragma unroll 8
    for (int yc = 0; yc < NCH; ++yc)
        s += partial[((size_t)yc * Cc + a) * Xc + x];

    // Block softmax over 1024 lanes (16 waves).
    float mx = waveReduceMax(s);
    if (lane == 0) smax[wave] = mx;
    __syncthreads();
#pragma unroll
    for (int i = 0; i < 16; ++i) mx = fmaxf(mx, smax[i]);

    const float e = __expf(s - mx);
    float sum = waveReduceSum(e);
    if (lane == 0) ssum[wave] = sum;
    __syncthreads();
    sum = 0.0f;
#pragma unroll
    for (int i = 0; i < 16; ++i) sum += ssum[i];

    const float p  = e / sum;
    const float bi = bias[x];

    // actions is block-uniform scalar; each b handled by exactly one block.
    for (int b = 0; b < Bc; ++b) {
        if (actions[b] == a) {
            float acc = 0.0f;
#pragma unroll 8
            for (int yc = 0; yc < NCH; ++yc)
                acc += partial[((size_t)yc * Cc + Ac + b) * Xc + x];
            Wy[b * Xc + x] = fmaf(acc, p, bi);
        }
    }
}

// ---------------------------------------------------------------------------
// k3: xWy[b,l] = sum_x x[b,l,x] * Wy[b,x]. Streams all 128 MB of x — the
// HBM-bound term (~19 us floor at 7 TB/s). R2-measured-best shape:
// grid (L/16, B) = 2048 blocks, 4 waves; each wave 4 rows.
// ---------------------------------------------------------------------------
__global__ __launch_bounds__(256) void k3_dot(
        const float* __restrict__ x, const float* __restrict__ Wy,
        float* __restrict__ xWy) {
    const int b  = blockIdx.y;
    const int l0 = blockIdx.x * 16;
    __shared__ float WyS[Xc];

    ((float4*)WyS)[threadIdx.x] = ((const float4*)(Wy + (size_t)b * Xc))[threadIdx.x];
    __syncthreads();

    const int wave = threadIdx.x >> 6;
    const int lane = threadIdx.x & 63;
    const float4* WyV = (const float4*)WyS;

    for (int r = wave; r < 16; r += 4) {
        const int l = l0 + r;
        const float4* xp = (const float4*)(x + ((size_t)b * Lc + l) * Xc);
        float acc = 0.0f;
#pragma unroll
        for (int k = 0; k < 4; ++k) {
            const int idx = lane + k * 64;
            const float4 xv = xp[idx];
            const float4 wv = WyV[idx];
            acc = fmaf(xv.x, wv.x, acc);
            acc = fmaf(xv.y, wv.y, acc);
            acc = fmaf(xv.z, wv.z, acc);
            acc = fmaf(xv.w, wv.w, acc);
        }
        acc = waveReduceSum(acc);
        if (lane == 0) xWy[b * Lc + l] = acc;
    }
}

// ---------------------------------------------------------------------------
// k4: out[b,:] = log_softmax_L(where(mask, -inf, xWy[b,:])). grid: B blocks.
// ---------------------------------------------------------------------------
__global__ __launch_bounds__(256) void k4_logsoftmax(
        const float* __restrict__ xWy, const unsigned char* __restrict__ mask,
        float* __restrict__ out) {
    const int b    = blockIdx.x;
    const int tid  = threadIdx.x;
    const int wave = tid >> 6;
    const int lane = tid & 63;
    __shared__ float smax[4];
    __shared__ float ssum[4];

    float v[4];
    float mx = -INFINITY;
#pragma unroll
    for (int k = 0; k < 4; ++k) {
        const int l = tid + k * 256;
        float t = xWy[b * Lc + l];
        if (mask[b * Lc + l]) t = -INFINITY;
        v[k] = t;
        mx = fmaxf(mx, t);
    }
    mx = waveReduceMax(mx);
    if (lane == 0) smax[wave] = mx;
    __syncthreads();
    mx = fmaxf(fmaxf(smax[0], smax[1]), fmaxf(smax[2], smax[3]));

    float sum = 0.0f;
#pragma unroll
    for (int k = 0; k < 4; ++k) sum += __expf(v[k] - mx);
    sum = waveReduceSum(sum);
    if (lane == 0) ssum[wave] = sum;
    __syncthreads();
    sum = ssum[0] + ssum[1] + ssum[2] + ssum[3];

    const float lse = mx + __logf(sum);
#pragma unroll
    for (int k = 0; k < 4; ++k) out[b * Lc + tid + k * 256] = v[k] - lse;
}

// ---------------------------------------------------------------------------
// Launch. Inputs (setup_inputs order):
//   0 x      [B,L,X] f32      1 y      [B,Y] f32     2 x_mask [B,L] bool
//   3 actions[B] int32        4 weight [Y,X] f32     5 bias   [X] f32
//   6 wa_h   [A,Y,1] f32
// Output: [B,L] f32 log-softmax.
// Workspace layout (no zero-init needed — every buffer fully overwritten
// before it is read):
//   [0, 12M)        partial [64][48][1024] f32  (k1 -> k2)
//   [12M, 12M+128K) Wy      B*X f32             (k2 -> k3)
//   [+128K, +256K)  xWy     B*L f32             (k3 -> k4)
// ---------------------------------------------------------------------------
extern "C" void kernel_launch(void* const* d_in, const int* in_sizes, int n_in,
                              void* d_out, int out_size, void* d_ws, size_t ws_size,
                              hipStream_t stream) {
    const float* x          = (const float*)d_in[0];
    const float* yv         = (const float*)d_in[1];
    const unsigned char* xm = (const unsigned char*)d_in[2];
    const int* actions      = (const int*)d_in[3];
    const float* weight     = (const float*)d_in[4];
    const float* bias       = (const float*)d_in[5];
    const float* wa_h       = (const float*)d_in[6];
    float* out              = (float*)d_out;

    char* ws       = (char*)d_ws;
    float* partial = (float*)(ws);
    float* Wy      = (float*)(ws + (size_t)NCH * Cc * Xc * 4);
    float* xWy     = (float*)(ws + (size_t)NCH * Cc * Xc * 4 + 128 * 1024);

    k1_proj<<<dim3(Xc / 256, NCH), 256, 0, stream>>>(weight, yv, wa_h, partial);
    k2_softmax_wy<<<Ac, 1024, 0, stream>>>(partial, bias, actions, Wy);
    k3_dot<<<dim3(Lc / 16, Bc), 256, 0, stream>>>(x, Wy, xWy);
    k4_logsoftmax<<<Bc, 256, 0, stream>>>(xWy, xm, out);
}

// Round 6
// 213.030 us; speedup vs baseline: 1.1173x; 1.1173x over previous
//
#include <hip/hip_runtime.h>
#include <hip/hip_bf16.h>
#include <math.h>

// Problem constants (fixed by the reference).
constexpr int Ac = 16;    // actions
constexpr int Bc = 32;    // batch
constexpr int Lc = 1024;  // sequence
constexpr int Xc = 1024;  // x feature
constexpr int Yc = 1024;  // y feature
constexpr int Cc = Ac + Bc;  // 48 combined coefficient rows

// Native clang vector type — __builtin_nontemporal_load requires this
// (HIP_vector_type float4 is a struct and is rejected).
typedef float vfloat4 __attribute__((ext_vector_type(4)));

// ---------------------------------------------------------------------------
// Wave/block reduction helpers (wave = 64 lanes on CDNA)
// ---------------------------------------------------------------------------
__device__ __forceinline__ float waveReduceSum(float v) {
#pragma unroll
    for (int off = 32; off > 0; off >>= 1) v += __shfl_down(v, off, 64);
    return v;
}

__device__ __forceinline__ float waveReduceMax(float v) {
#pragma unroll
    for (int off = 32; off > 0; off >>= 1) v = fmaxf(v, __shfl_down(v, off, 64));
    return v;
}

// ---------------------------------------------------------------------------
// k1: O[48,X] = C[48,Y] @ W[Y,X]; C rows 0..15 = wa_h, rows 16..47 = y.
// O rows 0..15 -> s_raw (pre-softmax scores), rows 16..47 -> yW.
// grid (X/256=4, Y/32=32) = 128 blocks. Coef chunk [48x32] in LDS,
// 32 weight values prefetched per thread, 1536 FMAs, 48 atomicAdds.
// (R4 post-mortem: atomic split-K beats materialized partials — partials
// cost 24 MB HBM round-trip + a 16-CU reduce. 32-chunks halves the R2
// atomic traffic to 6 MB / 32-way contention per cell.)
// ---------------------------------------------------------------------------
__global__ __launch_bounds__(256) void k1_proj(
        const float* __restrict__ weight, const float* __restrict__ yv,
        const float* __restrict__ wa_h, float* __restrict__ s_raw,
        float* __restrict__ yW) {
    const int x  = blockIdx.x * 256 + threadIdx.x;
    const int y0 = blockIdx.y * 32;

    __shared__ float cLDS[Cc][32];  // 6 KiB

    // Cooperative coef load: 1536 elements, 6 per thread (coalesced).
#pragma unroll
    for (int k = 0; k < 6; ++k) {
        const int idx = threadIdx.x + k * 256;
        const int row = idx >> 5;
        const int col = idx & 31;
        cLDS[row][col] = (row < Ac) ? wa_h[row * Yc + y0 + col]
                                    : yv[(row - Ac) * Yc + y0 + col];
    }

    // Prefetch this thread's 32 weight values (independent, coalesced).
    float w[32];
#pragma unroll
    for (int t = 0; t < 32; ++t) w[t] = weight[(size_t)(y0 + t) * Xc + x];

    __syncthreads();

    float acc[Cc];
#pragma unroll
    for (int j = 0; j < Cc; ++j) acc[j] = 0.0f;

    const float4* cvec = (const float4*)cLDS;
#pragma unroll
    for (int j = 0; j < Cc; ++j) {
#pragma unroll
        for (int q = 0; q < 8; ++q) {
            const float4 c = cvec[j * 8 + q];  // LDS b128 broadcast (free)
            acc[j] = fmaf(w[q * 4 + 0], c.x, acc[j]);
            acc[j] = fmaf(w[q * 4 + 1], c.y, acc[j]);
            acc[j] = fmaf(w[q * 4 + 2], c.z, acc[j]);
            acc[j] = fmaf(w[q * 4 + 3], c.w, acc[j]);
        }
    }

#pragma unroll
    for (int j = 0; j < Ac; ++j) atomicAdd(&s_raw[j * Xc + x], acc[j]);
#pragma unroll
    for (int j = Ac; j < Cc; ++j) atomicAdd(&yW[(j - Ac) * Xc + x], acc[j]);
}

// ---------------------------------------------------------------------------
// k2: score2[a,:] = softmax_x(s_raw[a,:]). grid: A blocks x 256 threads.
// (Exact R2-measured-best version.)
// ---------------------------------------------------------------------------
__global__ __launch_bounds__(256) void k2_softmax(
        const float* __restrict__ s_raw, float* __restrict__ score2) {
    const int a    = blockIdx.x;
    const int tid  = threadIdx.x;
    const int wave = tid >> 6;
    const int lane = tid & 63;
    __shared__ float smax[4];
    __shared__ float ssum[4];

    float v[4];
    float mx = -INFINITY;
#pragma unroll
    for (int k = 0; k < 4; ++k) {
        v[k] = s_raw[a * Xc + tid + k * 256];
        mx = fmaxf(mx, v[k]);
    }
    mx = waveReduceMax(mx);
    if (lane == 0) smax[wave] = mx;
    __syncthreads();
    mx = fmaxf(fmaxf(smax[0], smax[1]), fmaxf(smax[2], smax[3]));

    float sum = 0.0f;
#pragma unroll
    for (int k = 0; k < 4; ++k) {
        v[k] = __expf(v[k] - mx);
        sum += v[k];
    }
    sum = waveReduceSum(sum);
    if (lane == 0) ssum[wave] = sum;
    __syncthreads();
    sum = ssum[0] + ssum[1] + ssum[2] + ssum[3];

    const float inv = 1.0f / sum;
#pragma unroll
    for (int k = 0; k < 4; ++k) score2[a * Xc + tid + k * 256] = v[k] * inv;
}

// ---------------------------------------------------------------------------
// k3: xWy[b,l] = sum_x x[b,l,x] * Wy[b,x],
//     Wy[b,x] = yW[b,x]*score2[actions[b],x] + bias[x]  (built once in LDS).
// grid: (L/16, B) = 2048 blocks, 4 waves; each wave 4 rows. Streams all
// 128 MB of x (HBM floor ~19 us) — nontemporal: x has zero reuse, skip L2.
// (Exact R2-measured-best shape.)
// ---------------------------------------------------------------------------
__global__ __launch_bounds__(256) void k3_dot(
        const float* __restrict__ x, const float* __restrict__ yW,
        const float* __restrict__ score2, const float* __restrict__ bias,
        const int* __restrict__ actions, float* __restrict__ xWy) {
    const int b  = blockIdx.y;
    const int l0 = blockIdx.x * 16;
    __shared__ float Wy[Xc];

    const int act = actions[b];
#pragma unroll
    for (int k = 0; k < 4; ++k) {
        const int xi = threadIdx.x + k * 256;
        Wy[xi] = fmaf(yW[b * Xc + xi], score2[act * Xc + xi], bias[xi]);
    }
    __syncthreads();

    const int wave = threadIdx.x >> 6;
    const int lane = threadIdx.x & 63;
    const float4* WyV = (const float4*)Wy;

    for (int r = wave; r < 16; r += 4) {
        const int l = l0 + r;
        const vfloat4* xp = (const vfloat4*)(x + ((size_t)b * Lc + l) * Xc);
        float acc = 0.0f;
#pragma unroll
        for (int k = 0; k < 4; ++k) {
            const int idx = lane + k * 64;
            const vfloat4 xv = __builtin_nontemporal_load(&xp[idx]);
            const float4 wv = WyV[idx];
            acc = fmaf(xv.x, wv.x, acc);
            acc = fmaf(xv.y, wv.y, acc);
            acc = fmaf(xv.z, wv.z, acc);
            acc = fmaf(xv.w, wv.w, acc);
        }
        acc = waveReduceSum(acc);
        if (lane == 0) xWy[b * Lc + l] = acc;
    }
}

// ---------------------------------------------------------------------------
// k4: out[b,:] = log_softmax_L(where(mask, -inf, xWy[b,:])). grid: B blocks.
// ---------------------------------------------------------------------------
__global__ __launch_bounds__(256) void k4_logsoftmax(
        const float* __restrict__ xWy, const unsigned char* __restrict__ mask,
        float* __restrict__ out) {
    const int b    = blockIdx.x;
    const int tid  = threadIdx.x;
    const int wave = tid >> 6;
    const int lane = tid & 63;
    __shared__ float smax[4];
    __shared__ float ssum[4];

    float v[4];
    float mx = -INFINITY;
#pragma unroll
    for (int k = 0; k < 4; ++k) {
        const int l = tid + k * 256;
        float t = xWy[b * Lc + l];
        if (mask[b * Lc + l]) t = -INFINITY;
        v[k] = t;
        mx = fmaxf(mx, t);
    }
    mx = waveReduceMax(mx);
    if (lane == 0) smax[wave] = mx;
    __syncthreads();
    mx = fmaxf(fmaxf(smax[0], smax[1]), fmaxf(smax[2], smax[3]));

    float sum = 0.0f;
#pragma unroll
    for (int k = 0; k < 4; ++k) sum += __expf(v[k] - mx);
    sum = waveReduceSum(sum);
    if (lane == 0) ssum[wave] = sum;
    __syncthreads();
    sum = ssum[0] + ssum[1] + ssum[2] + ssum[3];

    const float lse = mx + __logf(sum);
#pragma unroll
    for (int k = 0; k < 4; ++k) out[b * Lc + tid + k * 256] = v[k] - lse;
}

// ---------------------------------------------------------------------------
// Launch. Inputs (setup_inputs order):
//   0 x      [B,L,X] f32      1 y      [B,Y] f32     2 x_mask [B,L] bool
//   3 actions[B] int32        4 weight [Y,X] f32     5 bias   [X] f32
//   6 wa_h   [A,Y,1] f32
// Output: [B,L] f32 log-softmax.
// Workspace layout:
//   [0,64K)     s_raw   A*X f32   (atomic-accumulated, zeroed below)
//   [64K,192K)  yW      B*X f32   (atomic-accumulated, zeroed below)
//   [192K,256K) score2  A*X f32
//   [256K,384K) xWy     B*L f32
// ---------------------------------------------------------------------------
extern "C" void kernel_launch(void* const* d_in, const int* in_sizes, int n_in,
                              void* d_out, int out_size, void* d_ws, size_t ws_size,
                              hipStream_t stream) {
    const float* x          = (const float*)d_in[0];
    const float* yv         = (const float*)d_in[1];
    const unsigned char* xm = (const unsigned char*)d_in[2];
    const int* actions      = (const int*)d_in[3];
    const float* weight     = (const float*)d_in[4];
    const float* bias       = (const float*)d_in[5];
    const float* wa_h       = (const float*)d_in[6];
    float* out              = (float*)d_out;

    char* ws      = (char*)d_ws;
    float* s_raw  = (float*)(ws);
    float* yW     = (float*)(ws + 64 * 1024);
    float* score2 = (float*)(ws + 192 * 1024);
    float* xWy    = (float*)(ws + 256 * 1024);

    // Zero only the atomic accumulation buffers (192 KiB).
    (void)hipMemsetAsync(d_ws, 0, 192 * 1024, stream);

    k1_proj<<<dim3(Xc / 256, Yc / 32), 256, 0, stream>>>(weight, yv, wa_h, s_raw, yW);
    k2_softmax<<<Ac, 256, 0, stream>>>(s_raw, score2);
    k3_dot<<<dim3(Lc / 16, Bc), 256, 0, stream>>>(x, yW, score2, bias, actions, xWy);
    k4_logsoftmax<<<Bc, 256, 0, stream>>>(xWy, xm, out);
}